// Round 6
// baseline (233.934 us; speedup 1.0000x reference)
//
#include <hip/hip_runtime.h>

#define NBINS 2048
#define BPB   64
#define TPB   256
#define NB    8

// speculative value window = bins [1832, 1857) of 2048 -> exact dyadic floats
#define WLO 0.89453125f       // 1832/2048
#define WHI 0.90673828125f    // 1857/2048

#define PCAP  57344   // spec pairs per batch (avg ~51K, +28 sigma)
#define LCAP  1536    // per-block spec staging (avg ~790)
#define FB_PCAP 8192  // fallback pairs per batch
#define FB_LCAP 512
#define CCAP  512     // select compact buffer

static __device__ __forceinline__ unsigned bucketOf(float v) {
    unsigned b = (unsigned)(v * (float)NBINS);
    return b > (NBINS - 1) ? (NBINS - 1) : b;
}

// inline-asm global load: compiler cannot sink/serialize these
static __device__ __forceinline__ void gload4(float4& d, const float4* a) {
    asm volatile("global_load_dwordx4 %0, %1, off" : "=v"(d) : "v"(a));
}
#define WAIT_VMCNT(N)                                              \
    do {                                                           \
        asm volatile("s_waitcnt vmcnt(" #N ")" ::: "memory");      \
        __builtin_amdgcn_sched_barrier(0);                         \
    } while (0)

#define ISSUE(SET, c)                                                    \
    do {                                                                 \
        const float4* tb_ = t4 + i0 + (c) * 4 * S;                       \
        const float4* pb_ = p4 + i0 + (c) * 4 * S;                       \
        gload4(t##SET##0, tb_);         gload4(t##SET##1, tb_ + S);      \
        gload4(t##SET##2, tb_ + 2 * S); gload4(t##SET##3, tb_ + 3 * S);  \
        gload4(p##SET##0, pb_);         gload4(p##SET##1, pb_ + S);      \
        gload4(p##SET##2, pb_ + 2 * S); gload4(p##SET##3, pb_ + 3 * S);  \
    } while (0)

#define PIPELINE8(PROC)                      \
    ISSUE(A, 0);                             \
    ISSUE(B, 1); WAIT_VMCNT(8); PROC(A);     \
    ISSUE(A, 2); WAIT_VMCNT(8); PROC(B);     \
    ISSUE(B, 3); WAIT_VMCNT(8); PROC(A);     \
    ISSUE(A, 4); WAIT_VMCNT(8); PROC(B);     \
    ISSUE(B, 5); WAIT_VMCNT(8); PROC(A);     \
    ISSUE(A, 6); WAIT_VMCNT(8); PROC(B);     \
    ISSUE(B, 7); WAIT_VMCNT(8); PROC(A);     \
    WAIT_VMCNT(0); PROC(B);

// cnt layout per batch b (8 u32): 0 nv_t, 1 nv_p, 2 inW_t, 3 inW_p, 4 abv_t, 5 abv_p, 6 naa, 7 npairs
// sinfo (u32): [0]=ok flag; per bt at 8+bt*8: 0 k, 1 frac bits, 2 below, 3 nv, 4 abv

// ---------- k_main: single full read; SSE + window stats + pair compact ----------
__global__ __launch_bounds__(TPB) void k_main(const float* __restrict__ pred,
                                              const float* __restrict__ targ,
                                              int nvec,
                                              double* __restrict__ sse,
                                              unsigned* __restrict__ cnt,
                                              unsigned* __restrict__ oflow,
                                              float2* __restrict__ pairs)
{
    __shared__ float2   sbuf[LCAP];
    __shared__ unsigned scnt, sbase;
    if (threadIdx.x == 0) scnt = 0;
    __syncthreads();

    const int b = blockIdx.y;
    const float4* __restrict__ p4 = (const float4*)pred + (size_t)b * nvec;
    const float4* __restrict__ t4 = (const float4*)targ + (size_t)b * nvec;

    float    lsse = 0.f;
    unsigned lnvt = 0, lnvp = 0, linwt = 0, linwp = 0, labvt = 0, labvp = 0, lnaa = 0;
    const int S  = BPB * TPB;
    const int i0 = blockIdx.x * TPB + threadIdx.x;

#define PELM(tq, pq)                                                         \
    {                                                                        \
        float tv[4] = {tq.x, tq.y, tq.z, tq.w};                              \
        float pv[4] = {pq.x, pq.y, pq.z, pq.w};                              \
        _Pragma("unroll")                                                    \
        for (int j = 0; j < 4; ++j) {                                        \
            float tt = tv[j], pp = pv[j];                                    \
            if (tt > 0.01f) {                                                \
                float d = pp - tt;                                           \
                lsse += d * d; lnvt++;                                       \
                bool pz = (pp > 0.f); if (pz) lnvp++;                        \
                bool tin = (tt >= WLO) && (tt < WHI);                        \
                bool pin = pz && (pp >= WLO) && (pp < WHI);                  \
                bool tab = (tt >= WHI);                                      \
                bool pab = (pp >= WHI);                                      \
                if (tin) linwt++;                                            \
                if (pin) linwp++;                                            \
                if (tab) labvt++;                                            \
                if (pab) labvp++;                                            \
                if (tab && pab) lnaa++;                                      \
                if (tin || pin) {                                            \
                    unsigned idx = atomicAdd(&scnt, 1u);                     \
                    if (idx < LCAP) sbuf[idx] = make_float2(tt, pp);         \
                }                                                            \
            }                                                                \
        }                                                                    \
    }
#define PROCM(SET)                                               \
    {                                                            \
        PELM(t##SET##0, p##SET##0); PELM(t##SET##1, p##SET##1);  \
        PELM(t##SET##2, p##SET##2); PELM(t##SET##3, p##SET##3);  \
    }

    float4 tA0, tA1, tA2, tA3, pA0, pA1, pA2, pA3;
    float4 tB0, tB1, tB2, tB3, pB0, pB1, pB2, pB3;
    PIPELINE8(PROCM)
#undef PROCM
#undef PELM
    __syncthreads();

    if (threadIdx.x == 0) {
        unsigned n = scnt;
        if (n > LCAP) { atomicOr(oflow, 1u); n = LCAP; }
        sbase = atomicAdd(&cnt[b * 8 + 7], n);
        scnt = n;
    }
    __syncthreads();
    for (unsigned k = threadIdx.x; k < scnt; k += TPB) {
        unsigned idx = sbase + k;
        if (idx < PCAP) pairs[(size_t)b * PCAP + idx] = sbuf[k];
    }

    for (int off = 32; off; off >>= 1) {
        lsse  += __shfl_down(lsse, off);
        lnvt  += __shfl_down(lnvt, off);
        lnvp  += __shfl_down(lnvp, off);
        linwt += __shfl_down(linwt, off);
        linwp += __shfl_down(linwp, off);
        labvt += __shfl_down(labvt, off);
        labvp += __shfl_down(labvp, off);
        lnaa  += __shfl_down(lnaa, off);
    }
    if ((threadIdx.x & 63) == 0) {
        atomicAdd(&sse[b], (double)lsse);
        atomicAdd(&cnt[b * 8 + 0], lnvt);
        atomicAdd(&cnt[b * 8 + 1], lnvp);
        atomicAdd(&cnt[b * 8 + 2], linwt);
        atomicAdd(&cnt[b * 8 + 3], linwp);
        atomicAdd(&cnt[b * 8 + 4], labvt);
        atomicAdd(&cnt[b * 8 + 5], labvp);
        atomicAdd(&cnt[b * 8 + 6], lnaa);
    }
}

// ---------- k_check: validate speculation, compute ranks ----------
__global__ __launch_bounds__(64) void k_check(const unsigned* __restrict__ cnt,
                                              const unsigned* __restrict__ oflow,
                                              unsigned* __restrict__ sinfo)
{
    __shared__ unsigned okarr[16];
    const int bt = threadIdx.x;
    if (bt < 16) {
        const int b = bt >> 1, t = bt & 1;
        unsigned nv  = cnt[b * 8 + t];
        unsigned inW = cnt[b * 8 + 2 + t];
        unsigned abv = cnt[b * 8 + 4 + t];
        unsigned below = nv - inW - abv;
        unsigned ok = 0, k = 0; float frac = 0.f;
        if (nv > 0 && inW > 0) {
            double pos = 0.9 * (double)(nv - 1);
            k = (unsigned)pos;
            frac = (float)(pos - (double)k);
            if (k >= below && (k + 1) <= below + inW - 1) ok = 1;
        }
        if (cnt[b * 8 + 7] > PCAP) ok = 0;
        if (*oflow) ok = 0;
        unsigned* si = sinfo + 8 + bt * 8;
        si[0] = k;
        si[1] = __float_as_uint(frac);
        si[2] = below;
        si[3] = nv;
        si[4] = abv;
        okarr[bt] = ok;
    }
    __syncthreads();
    if (threadIdx.x == 0) {
        unsigned ok = 1;
        for (int i = 0; i < 16; ++i) ok &= okarr[i];
        sinfo[0] = ok;
    }
}

// ---------- fallback: full histogram (early-exit when speculation ok) ----------
__global__ __launch_bounds__(TPB) void k_hist_fb(const float* __restrict__ pred,
                                                 const float* __restrict__ targ,
                                                 int nvec,
                                                 const unsigned* __restrict__ sinfo,
                                                 unsigned short* __restrict__ hist16)
{
    if (sinfo[0]) return;
    __shared__ unsigned h[2 * NBINS];
    for (int k = threadIdx.x; k < 2 * NBINS; k += TPB) h[k] = 0u;
    __syncthreads();

    const int b = blockIdx.y;
    const float4* __restrict__ p4 = (const float4*)pred + (size_t)b * nvec;
    const float4* __restrict__ t4 = (const float4*)targ + (size_t)b * nvec;
    const int S  = BPB * TPB;
    const int i0 = blockIdx.x * TPB + threadIdx.x;

#define PELH(tq, pq)                                             \
    {                                                            \
        float tv[4] = {tq.x, tq.y, tq.z, tq.w};                  \
        float pv[4] = {pq.x, pq.y, pq.z, pq.w};                  \
        _Pragma("unroll")                                        \
        for (int j = 0; j < 4; ++j) {                            \
            float tt = tv[j], pp = pv[j];                        \
            if (tt > 0.01f) {                                    \
                atomicAdd(&h[bucketOf(tt)], 1u);                 \
                if (pp > 0.f)                                    \
                    atomicAdd(&h[NBINS + bucketOf(pp)], 1u);     \
            }                                                    \
        }                                                        \
    }
#define PROCH(SET)                                               \
    {                                                            \
        PELH(t##SET##0, p##SET##0); PELH(t##SET##1, p##SET##1);  \
        PELH(t##SET##2, p##SET##2); PELH(t##SET##3, p##SET##3);  \
    }
    float4 tA0, tA1, tA2, tA3, pA0, pA1, pA2, pA3;
    float4 tB0, tB1, tB2, tB3, pB0, pB1, pB2, pB3;
    PIPELINE8(PROCH)
#undef PROCH
#undef PELH
    __syncthreads();

    unsigned short* gh = hist16 + ((size_t)b * BPB + blockIdx.x) * (2 * NBINS);
    ushort4* gh4 = (ushort4*)gh;
    for (int k = threadIdx.x; k < (2 * NBINS) / 4; k += TPB) {
        ushort4 v;
        v.x = (unsigned short)h[4 * k + 0];
        v.y = (unsigned short)h[4 * k + 1];
        v.z = (unsigned short)h[4 * k + 2];
        v.w = (unsigned short)h[4 * k + 3];
        gh4[k] = v;
    }
}

// ---------- fallback: scan histogram -> binfo ----------
// binfo per bt (8 u32): 0 lo, 1 hi, 2 cum_below, 3 k, 4 frac, 5 nv
__global__ __launch_bounds__(256) void k_scan_fb(const unsigned short* __restrict__ hist16,
                                                 const unsigned* __restrict__ cnt,
                                                 const unsigned* __restrict__ sinfo,
                                                 unsigned* __restrict__ binfo)
{
    if (sinfo[0]) return;
    const int bt = blockIdx.x;
    const int b = bt >> 1, t = bt & 1;
    const unsigned nv = cnt[b * 8 + t];
    unsigned* bi = binfo + bt * 8;

    __shared__ unsigned partial[256];
    __shared__ unsigned sk, sr2;

    if (threadIdx.x == 0) {
        bi[5] = nv;
        if (nv == 0) {
            bi[0] = 0xFFFFFFFFu; bi[1] = 0xFFFFFFFFu;
            bi[2] = 0; bi[3] = 0; bi[4] = __float_as_uint(0.0f);
        } else {
            double pos  = 0.9 * (double)(nv - 1);
            unsigned k  = (unsigned)pos;
            bi[3] = k;
            bi[4] = __float_as_uint((float)(pos - (double)k));
            sk = k;
            sr2 = (k + 2 <= nv) ? (k + 2) : (k + 1);
        }
    }
    __syncthreads();
    if (nv == 0) return;

    const unsigned r1 = sk + 1, r2 = sr2;
    const int lo = threadIdx.x * (NBINS / 256);
    unsigned local[NBINS / 256];
#pragma unroll
    for (int j = 0; j < NBINS / 256; ++j) local[j] = 0;
    for (int rep = 0; rep < BPB; ++rep) {
        const ushort4* h4 = (const ushort4*)(hist16 +
            ((size_t)b * BPB + rep) * (2 * NBINS) + (size_t)t * NBINS + lo);
        ushort4 a = h4[0], c = h4[1];
        local[0] += a.x; local[1] += a.y; local[2] += a.z; local[3] += a.w;
        local[4] += c.x; local[5] += c.y; local[6] += c.z; local[7] += c.w;
    }
    unsigned ls = 0;
#pragma unroll
    for (int j = 0; j < NBINS / 256; ++j) ls += local[j];
    partial[threadIdx.x] = ls;
    __syncthreads();
    for (int off = 1; off < 256; off <<= 1) {
        unsigned v = (threadIdx.x >= (unsigned)off) ? partial[threadIdx.x - off] : 0u;
        __syncthreads();
        partial[threadIdx.x] += v;
        __syncthreads();
    }
    unsigned run = partial[threadIdx.x] - ls;
#pragma unroll
    for (int j = 0; j < NBINS / 256; ++j) {
        unsigned c = local[j];
        if (c) {
            if (run < r1 && run + c >= r1) { bi[0] = lo + j; bi[2] = run; }
            if (run < r2 && run + c >= r2) { bi[1] = lo + j; }
        }
        run += c;
    }
}

// ---------- fallback: compact by bucket range ----------
__global__ __launch_bounds__(TPB) void k_compact_fb(const float* __restrict__ pred,
                                                    const float* __restrict__ targ,
                                                    int nvec,
                                                    const unsigned* __restrict__ sinfo,
                                                    const unsigned* __restrict__ binfo,
                                                    unsigned* __restrict__ fb_npairs,
                                                    unsigned* __restrict__ fb_naa,
                                                    float2* __restrict__ fb_pairs)
{
    if (sinfo[0]) return;
    __shared__ float2   sbuf[FB_LCAP];
    __shared__ unsigned scnt, sbase;
    if (threadIdx.x == 0) scnt = 0;
    __syncthreads();

    const int b = blockIdx.y;
    const unsigned lo_t = binfo[(2 * b + 0) * 8 + 0], hi_t = binfo[(2 * b + 0) * 8 + 1];
    const unsigned lo_p = binfo[(2 * b + 1) * 8 + 0], hi_p = binfo[(2 * b + 1) * 8 + 1];

    const float4* __restrict__ p4 = (const float4*)pred + (size_t)b * nvec;
    const float4* __restrict__ t4 = (const float4*)targ + (size_t)b * nvec;
    unsigned laa = 0;
    const int S  = BPB * TPB;
    const int i0 = blockIdx.x * TPB + threadIdx.x;

#define PELC(tq, pq)                                                      \
    {                                                                     \
        float tv[4] = {tq.x, tq.y, tq.z, tq.w};                           \
        float pv[4] = {pq.x, pq.y, pq.z, pq.w};                           \
        _Pragma("unroll")                                                 \
        for (int j = 0; j < 4; ++j) {                                     \
            float tt = tv[j], pp = pv[j];                                 \
            if (tt > 0.01f) {                                             \
                unsigned at = bucketOf(tt);                               \
                bool t_in = (at >= lo_t) && (at <= hi_t);                 \
                bool t_ab = (at > hi_t);                                  \
                bool ppos = (pp > 0.f);                                   \
                unsigned ap = bucketOf(pp);                               \
                bool p_in = ppos && (ap >= lo_p) && (ap <= hi_p);         \
                bool p_ab = ppos && (ap > hi_p);                          \
                if (t_ab && p_ab) laa++;                                  \
                if (t_in || p_in) {                                       \
                    unsigned idx = atomicAdd(&scnt, 1u);                  \
                    if (idx < FB_LCAP) sbuf[idx] = make_float2(tt, pp);   \
                }                                                         \
            }                                                             \
        }                                                                 \
    }
#define PROCC(SET)                                               \
    {                                                            \
        PELC(t##SET##0, p##SET##0); PELC(t##SET##1, p##SET##1);  \
        PELC(t##SET##2, p##SET##2); PELC(t##SET##3, p##SET##3);  \
    }
    float4 tA0, tA1, tA2, tA3, pA0, pA1, pA2, pA3;
    float4 tB0, tB1, tB2, tB3, pB0, pB1, pB2, pB3;
    PIPELINE8(PROCC)
#undef PROCC
#undef PELC
    __syncthreads();
    if (threadIdx.x == 0) {
        unsigned n = scnt < FB_LCAP ? scnt : FB_LCAP;
        sbase = atomicAdd(&fb_npairs[b], n);
        scnt = n;
    }
    __syncthreads();
    for (unsigned k = threadIdx.x; k < scnt; k += TPB) {
        unsigned idx = sbase + k;
        if (idx < FB_PCAP) fb_pairs[(size_t)b * FB_PCAP + idx] = sbuf[k];
    }
    for (int off = 32; off; off >>= 1) laa += __shfl_down(laa, off);
    if ((threadIdx.x & 63) == 0 && laa) atomicAdd(&fb_naa[b], laa);
}

// ---------- k_select: refine-histogram -> exact order stats -> threshold + hot ----------
__global__ __launch_bounds__(1024) void k_select(const unsigned* __restrict__ sinfo,
                                                 const unsigned* __restrict__ cnt,
                                                 const float2* __restrict__ pairs,
                                                 const unsigned* __restrict__ binfo,
                                                 const unsigned* __restrict__ fb_npairs,
                                                 const float2* __restrict__ fb_pairs,
                                                 float* __restrict__ thr,
                                                 unsigned* __restrict__ hotc)
{
    __shared__ unsigned hc[2048];     // hist, then inclusive cum in-place
    __shared__ unsigned partial[1024];
    __shared__ float    sv[CCAP];
    __shared__ unsigned sb_lo, sb_hi, scc, scle;
    __shared__ float    sth;

    const int bt = blockIdx.x;
    const int b = bt >> 1, t = bt & 1;
    const unsigned ok = sinfo[0];

    unsigned k, below, nv;
    float frac, rlo, rhi;
    unsigned blo_bk = 0, bhi_bk = 0;
    const float2* src;
    unsigned np;

    if (ok) {
        const unsigned* si = sinfo + 8 + bt * 8;
        k = si[0]; frac = __uint_as_float(si[1]); below = si[2]; nv = si[3];
        rlo = WLO; rhi = WHI;
        src = pairs + (size_t)b * PCAP;
        np = cnt[b * 8 + 7]; if (np > PCAP) np = PCAP;
    } else {
        const unsigned* bi = binfo + bt * 8;
        nv = bi[5];
        if (nv == 0) {
            if (threadIdx.x == 0) { thr[bt] = 0.01f; hotc[bt] = 0; }
            return;
        }
        blo_bk = bi[0]; bhi_bk = bi[1]; below = bi[2]; k = bi[3];
        frac = __uint_as_float(bi[4]);
        rlo = (float)blo_bk * (1.0f / NBINS);
        rhi = (float)(bhi_bk + 1) * (1.0f / NBINS);
        src = fb_pairs + (size_t)b * FB_PCAP;
        np = fb_npairs[b]; if (np > FB_PCAP) np = FB_PCAP;
    }
    const float scale = 2048.0f / (rhi - rlo);

#define MEMB(v) (ok ? ((v) >= WLO && (v) < WHI)                                   \
                    : ((v) > 0.f && bucketOf(v) >= blo_bk && bucketOf(v) <= bhi_bk))

    for (int i = threadIdx.x; i < 2048; i += 1024) hc[i] = 0u;
    if (threadIdx.x == 0) { sb_lo = 0xFFFFFFFFu; sb_hi = 0xFFFFFFFFu; scc = 0; scle = 0; }
    __syncthreads();

    // phase A: refine histogram
    for (unsigned i = threadIdx.x; i < np; i += 1024) {
        float2 pr = src[i];
        float v = t ? pr.y : pr.x;
        if (MEMB(v)) {
            int bin = (int)((v - rlo) * scale);
            bin = bin < 0 ? 0 : (bin > 2047 ? 2047 : bin);
            atomicAdd(&hc[bin], 1u);
        }
    }
    __syncthreads();

    // inclusive prefix over 2048 bins (2 per thread)
    unsigned h0 = hc[2 * threadIdx.x], h1 = hc[2 * threadIdx.x + 1];
    unsigned ssum = h0 + h1;
    partial[threadIdx.x] = ssum;
    __syncthreads();
    for (int off = 1; off < 1024; off <<= 1) {
        unsigned v = (threadIdx.x >= (unsigned)off) ? partial[threadIdx.x - off] : 0u;
        __syncthreads();
        partial[threadIdx.x] += v;
        __syncthreads();
    }
    unsigned excl = partial[threadIdx.x] - ssum;
    hc[2 * threadIdx.x]     = excl + h0;
    hc[2 * threadIdx.x + 1] = excl + ssum;
    __syncthreads();

    // locate bins containing local ranks r+1, r+2
    const unsigned r  = k - below;
    const unsigned r1 = r + 1, r2 = r + 2;
    for (int j = 2 * threadIdx.x; j <= 2 * threadIdx.x + 1; ++j) {
        unsigned c = hc[j];
        unsigned prev = (j == 0) ? 0u : hc[j - 1];
        if (c >= r1 && prev < r1) atomicMin(&sb_lo, (unsigned)j);
        if (c >= r2 && prev < r2) atomicMin(&sb_hi, (unsigned)j);
    }
    __syncthreads();
    unsigned b_lo = sb_lo, b_hi = sb_hi;
    if (b_hi == 0xFFFFFFFFu) b_hi = 2047;
    if (b_lo == 0xFFFFFFFFu) b_lo = 2047;
    unsigned cumlo = (b_lo > 0) ? hc[b_lo - 1] : 0u;

    // phase B: compact values in [b_lo, b_hi]
    for (unsigned i = threadIdx.x; i < np; i += 1024) {
        float2 pr = src[i];
        float v = t ? pr.y : pr.x;
        if (MEMB(v)) {
            int bin = (int)((v - rlo) * scale);
            bin = bin < 0 ? 0 : (bin > 2047 ? 2047 : bin);
            if ((unsigned)bin >= b_lo && (unsigned)bin <= b_hi) {
                unsigned idx = atomicAdd(&scc, 1u);
                if (idx < CCAP) sv[idx] = v;
            }
        }
    }
    __syncthreads();
    unsigned n_cmp = scc < CCAP ? scc : CCAP;

    // odd-even transposition sort (n_cmp small, typically ~25)
    for (unsigned ph = 0; ph < n_cmp; ++ph) {
        unsigned idx = 2 * threadIdx.x + (ph & 1);
        if (idx + 1 < n_cmp) {
            float a = sv[idx], c = sv[idx + 1];
            if (a > c) { sv[idx] = c; sv[idx + 1] = a; }
        }
        __syncthreads();
    }

    if (threadIdx.x == 0) {
        long rl = (long)r - (long)cumlo;
        if (rl < 0) rl = 0;
        if (rl >= (long)n_cmp) rl = (long)n_cmp - 1;
        float v0 = sv[rl];
        float v1 = (rl + 1 < (long)n_cmp) ? sv[rl + 1] : v0;
        sth = v0 + frac * (v1 - v0);
        thr[bt] = sth;
    }
    __syncthreads();
    float th = sth;

    // phase C: tie-safe count of member values <= th
    unsigned cle = 0;
    for (unsigned i = threadIdx.x; i < np; i += 1024) {
        float2 pr = src[i];
        float v = t ? pr.y : pr.x;
        if (MEMB(v) && v <= th) cle++;
    }
    for (int off = 32; off; off >>= 1) cle += __shfl_down(cle, off);
    if ((threadIdx.x & 63) == 0 && cle) atomicAdd(&scle, cle);
    __syncthreads();
    if (threadIdx.x == 0) hotc[bt] = nv - below - scle;
#undef MEMB
}

// ---------- k_resolve: per-batch intersection + loss ----------
__global__ __launch_bounds__(256) void k_resolve(const unsigned* __restrict__ sinfo,
                                                 const double* __restrict__ sse,
                                                 const unsigned* __restrict__ cnt,
                                                 const float2* __restrict__ pairs,
                                                 const unsigned* __restrict__ fb_npairs,
                                                 const unsigned* __restrict__ fb_naa,
                                                 const float2* __restrict__ fb_pairs,
                                                 const float* __restrict__ thr,
                                                 const unsigned* __restrict__ hotc,
                                                 double* __restrict__ loss_part)
{
    __shared__ unsigned sI;
    if (threadIdx.x == 0) sI = 0;
    __syncthreads();
    const int b = blockIdx.x;
    const unsigned ok = sinfo[0];
    const float2* src = ok ? (pairs + (size_t)b * PCAP) : (fb_pairs + (size_t)b * FB_PCAP);
    unsigned np  = ok ? cnt[b * 8 + 7] : fb_npairs[b];
    unsigned cap = ok ? PCAP : FB_PCAP;
    if (np > cap) np = cap;
    unsigned naa = ok ? cnt[b * 8 + 6] : fb_naa[b];

    float th_t = thr[2 * b + 0], th_p = thr[2 * b + 1];
    unsigned c = 0;
    for (unsigned i = threadIdx.x; i < np; i += 256) {
        float2 pr = src[i];
        if (pr.x > th_t && pr.y > th_p) c++;
    }
    for (int off = 32; off; off >>= 1) c += __shfl_down(c, off);
    if ((threadIdx.x & 63) == 0 && c) atomicAdd(&sI, c);
    __syncthreads();
    if (threadIdx.x == 0) {
        double nv  = (double)cnt[b * 8 + 0];
        double mse = sse[b] / (nv + 1e-8);
        double T = (double)hotc[2 * b + 0];
        double P = (double)hotc[2 * b + 1];
        double I = (double)(naa + sI);
        double dice = 1.0 - 2.0 * I / (P + T + 1e-8);
        loss_part[b] = 0.5 * mse + 0.5 * dice;
    }
}

__global__ void k_final(const double* __restrict__ loss_part, float* __restrict__ out)
{
    if (threadIdx.x == 0 && blockIdx.x == 0) {
        double acc = 0.0;
        for (int b = 0; b < NB; ++b) acc += loss_part[b];
        out[0] = (float)(acc / (double)NB);
    }
}

// ---------- launcher ----------
extern "C" void kernel_launch(void* const* d_in, const int* in_sizes, int n_in,
                              void* d_out, int out_size, void* d_ws, size_t ws_size,
                              hipStream_t stream) {
    const float* pred = (const float*)d_in[0];
    const float* targ = (const float*)d_in[1];
    float* out = (float*)d_out;

    const int total = in_sizes[0];
    const int N     = total / NB;   // 2,097,152
    const int nvec  = N / 4;        // 524,288 == BPB*TPB*4*8 exactly

    // ws layout:
    // [0, 4194304): pairs_spec (8*57344*8 = 3,670,016) overlapped with fb hist16 (8*64*2*2048*2 = 4,194,304)
    char* ws = (char*)d_ws;
    float2*         pairs  = (float2*)(ws + 0);
    unsigned short* hist16 = (unsigned short*)(ws + 0);
    double*   sse       = (double*)  (ws + 4194304);
    unsigned* cnt       = (unsigned*)(ws + 4194368);
    unsigned* oflow     = (unsigned*)(ws + 4194624);
    unsigned* fb_naa    = (unsigned*)(ws + 4194688);
    unsigned* fb_npairs = (unsigned*)(ws + 4194752);
    double*   loss_part = (double*)  (ws + 4194816);
    unsigned* sinfo     = (unsigned*)(ws + 4194880);
    unsigned* binfo     = (unsigned*)(ws + 4195904);
    float*    thr       = (float*)   (ws + 4196416);
    unsigned* hotc      = (unsigned*)(ws + 4196480);
    float2*   fb_pairs  = (float2*)  (ws + 4196544);   // 8*8192*8 = 524,288 -> ends 4,720,832
    (void)ws_size; (void)n_in; (void)out_size;

    hipMemsetAsync(ws + 4194304, 0, 512, stream);  // sse, cnt, oflow, fb_naa, fb_npairs

    dim3 gs(BPB, NB);
    k_main      <<<gs, TPB, 0, stream>>>(pred, targ, nvec, sse, cnt, oflow, pairs);
    k_check     <<<1, 64, 0, stream>>>(cnt, oflow, sinfo);
    k_hist_fb   <<<gs, TPB, 0, stream>>>(pred, targ, nvec, sinfo, hist16);
    k_scan_fb   <<<2 * NB, 256, 0, stream>>>(hist16, cnt, sinfo, binfo);
    k_compact_fb<<<gs, TPB, 0, stream>>>(pred, targ, nvec, sinfo, binfo, fb_npairs, fb_naa, fb_pairs);
    k_select    <<<2 * NB, 1024, 0, stream>>>(sinfo, cnt, pairs, binfo, fb_npairs, fb_pairs, thr, hotc);
    k_resolve   <<<NB, 256, 0, stream>>>(sinfo, sse, cnt, pairs, fb_npairs, fb_naa, fb_pairs, thr, hotc, loss_part);
    k_final     <<<1, 64, 0, stream>>>(loss_part, out);
}

// Round 7
// 232.449 us; speedup vs baseline: 1.0064x; 1.0064x over previous
//
#include <hip/hip_runtime.h>

#define NBINS 2048
#define BPB   64
#define TPB   256
#define NB    8

// speculative value window = bins [1832, 1857) of 2048 -> exact dyadic floats
#define WLO 0.89453125f       // 1832/2048
#define WHI 0.90673828125f    // 1857/2048

#define PCAP  57344   // spec pairs per batch (avg ~51K, +28 sigma)
#define LCAP  1536    // per-block spec staging (avg ~790)
#define FB_PCAP 8192  // fallback pairs per batch
#define FB_LCAP 512
#define CCAP  512     // select compact buffer

static __device__ __forceinline__ unsigned bucketOf(float v) {
    unsigned b = (unsigned)(v * (float)NBINS);
    return b > (NBINS - 1) ? (NBINS - 1) : b;
}

// inline-asm global load: compiler cannot sink/serialize these
static __device__ __forceinline__ void gload4(float4& d, const float4* a) {
    asm volatile("global_load_dwordx4 %0, %1, off" : "=v"(d) : "v"(a));
}
#define WAIT_VMCNT(N)                                              \
    do {                                                           \
        asm volatile("s_waitcnt vmcnt(" #N ")" ::: "memory");      \
        __builtin_amdgcn_sched_barrier(0);                         \
    } while (0)

#define ISSUE(SET, c)                                                    \
    do {                                                                 \
        const float4* tb_ = t4 + i0 + (c) * 4 * S;                       \
        const float4* pb_ = p4 + i0 + (c) * 4 * S;                       \
        gload4(t##SET##0, tb_);         gload4(t##SET##1, tb_ + S);      \
        gload4(t##SET##2, tb_ + 2 * S); gload4(t##SET##3, tb_ + 3 * S);  \
        gload4(p##SET##0, pb_);         gload4(p##SET##1, pb_ + S);      \
        gload4(p##SET##2, pb_ + 2 * S); gload4(p##SET##3, pb_ + 3 * S);  \
    } while (0)

#define PIPELINE8(PROC)                      \
    ISSUE(A, 0);                             \
    ISSUE(B, 1); WAIT_VMCNT(8); PROC(A);     \
    ISSUE(A, 2); WAIT_VMCNT(8); PROC(B);     \
    ISSUE(B, 3); WAIT_VMCNT(8); PROC(A);     \
    ISSUE(A, 4); WAIT_VMCNT(8); PROC(B);     \
    ISSUE(B, 5); WAIT_VMCNT(8); PROC(A);     \
    ISSUE(A, 6); WAIT_VMCNT(8); PROC(B);     \
    ISSUE(B, 7); WAIT_VMCNT(8); PROC(A);     \
    WAIT_VMCNT(0); PROC(B);

// cnt layout per batch b (8 u32): 0 nv_t, 1 nv_p, 2 inW_t, 3 inW_p, 4 abv_t, 5 abv_p, 6 naa, 7 npairs
// sinfo (u32): [0]=ok flag; per bt at 8+bt*8: 0 k, 1 frac bits, 2 below, 3 nv, 4 abv

// ---------- k_main: single full read; SSE + window stats + pair compact ----------
// __launch_bounds__(TPB, 2): 2 waves/SIMD floor -> VGPR budget ~256, so the
// 64-VGPR asm pipeline is NOT spilled (R6 evidence: default bounds gave 44 VGPR
// = forced spill of pending-load dests = serialized pipeline).
__global__ __launch_bounds__(TPB, 2) void k_main(const float* __restrict__ pred,
                                                 const float* __restrict__ targ,
                                                 int nvec,
                                                 double* __restrict__ sse,
                                                 unsigned* __restrict__ cnt,
                                                 unsigned* __restrict__ oflow,
                                                 float2* __restrict__ pairs)
{
    __shared__ float2   sbuf[LCAP];
    __shared__ unsigned scnt, sbase;
    if (threadIdx.x == 0) scnt = 0;
    __syncthreads();

    const int b = blockIdx.y;
    const float4* __restrict__ p4 = (const float4*)pred + (size_t)b * nvec;
    const float4* __restrict__ t4 = (const float4*)targ + (size_t)b * nvec;

    float    lsse = 0.f;
    unsigned lnvt = 0, lnvp = 0, linwt = 0, linwp = 0, labvt = 0, labvp = 0, lnaa = 0;
    const int S  = BPB * TPB;
    const int i0 = blockIdx.x * TPB + threadIdx.x;

#define PELM(tq, pq)                                                         \
    {                                                                        \
        float tv[4] = {tq.x, tq.y, tq.z, tq.w};                              \
        float pv[4] = {pq.x, pq.y, pq.z, pq.w};                              \
        _Pragma("unroll")                                                    \
        for (int j = 0; j < 4; ++j) {                                        \
            float tt = tv[j], pp = pv[j];                                    \
            if (tt > 0.01f) {                                                \
                float d = pp - tt;                                           \
                lsse += d * d; lnvt++;                                       \
                bool pz = (pp > 0.f); if (pz) lnvp++;                        \
                bool tin = (tt >= WLO) && (tt < WHI);                        \
                bool pin = pz && (pp >= WLO) && (pp < WHI);                  \
                bool tab = (tt >= WHI);                                      \
                bool pab = (pp >= WHI);                                      \
                if (tin) linwt++;                                            \
                if (pin) linwp++;                                            \
                if (tab) labvt++;                                            \
                if (pab) labvp++;                                            \
                if (tab && pab) lnaa++;                                      \
                if (tin || pin) {                                            \
                    unsigned idx = atomicAdd(&scnt, 1u);                     \
                    if (idx < LCAP) sbuf[idx] = make_float2(tt, pp);         \
                }                                                            \
            }                                                                \
        }                                                                    \
    }
#define PROCM(SET)                                               \
    {                                                            \
        PELM(t##SET##0, p##SET##0); PELM(t##SET##1, p##SET##1);  \
        PELM(t##SET##2, p##SET##2); PELM(t##SET##3, p##SET##3);  \
    }

    float4 tA0, tA1, tA2, tA3, pA0, pA1, pA2, pA3;
    float4 tB0, tB1, tB2, tB3, pB0, pB1, pB2, pB3;
    PIPELINE8(PROCM)
#undef PROCM
#undef PELM
    __syncthreads();

    if (threadIdx.x == 0) {
        unsigned n = scnt;
        if (n > LCAP) { atomicOr(oflow, 1u); n = LCAP; }
        sbase = atomicAdd(&cnt[b * 8 + 7], n);
        scnt = n;
    }
    __syncthreads();
    for (unsigned k = threadIdx.x; k < scnt; k += TPB) {
        unsigned idx = sbase + k;
        if (idx < PCAP) pairs[(size_t)b * PCAP + idx] = sbuf[k];
    }

    for (int off = 32; off; off >>= 1) {
        lsse  += __shfl_down(lsse, off);
        lnvt  += __shfl_down(lnvt, off);
        lnvp  += __shfl_down(lnvp, off);
        linwt += __shfl_down(linwt, off);
        linwp += __shfl_down(linwp, off);
        labvt += __shfl_down(labvt, off);
        labvp += __shfl_down(labvp, off);
        lnaa  += __shfl_down(lnaa, off);
    }
    if ((threadIdx.x & 63) == 0) {
        atomicAdd(&sse[b], (double)lsse);
        atomicAdd(&cnt[b * 8 + 0], lnvt);
        atomicAdd(&cnt[b * 8 + 1], lnvp);
        atomicAdd(&cnt[b * 8 + 2], linwt);
        atomicAdd(&cnt[b * 8 + 3], linwp);
        atomicAdd(&cnt[b * 8 + 4], labvt);
        atomicAdd(&cnt[b * 8 + 5], labvp);
        atomicAdd(&cnt[b * 8 + 6], lnaa);
    }
}

// ---------- k_check: validate speculation, compute ranks ----------
__global__ __launch_bounds__(64) void k_check(const unsigned* __restrict__ cnt,
                                              const unsigned* __restrict__ oflow,
                                              unsigned* __restrict__ sinfo)
{
    __shared__ unsigned okarr[16];
    const int bt = threadIdx.x;
    if (bt < 16) {
        const int b = bt >> 1, t = bt & 1;
        unsigned nv  = cnt[b * 8 + t];
        unsigned inW = cnt[b * 8 + 2 + t];
        unsigned abv = cnt[b * 8 + 4 + t];
        unsigned below = nv - inW - abv;
        unsigned ok = 0, k = 0; float frac = 0.f;
        if (nv > 0 && inW > 0) {
            double pos = 0.9 * (double)(nv - 1);
            k = (unsigned)pos;
            frac = (float)(pos - (double)k);
            if (k >= below && (k + 1) <= below + inW - 1) ok = 1;
        }
        if (cnt[b * 8 + 7] > PCAP) ok = 0;
        if (*oflow) ok = 0;
        unsigned* si = sinfo + 8 + bt * 8;
        si[0] = k;
        si[1] = __float_as_uint(frac);
        si[2] = below;
        si[3] = nv;
        si[4] = abv;
        okarr[bt] = ok;
    }
    __syncthreads();
    if (threadIdx.x == 0) {
        unsigned ok = 1;
        for (int i = 0; i < 16; ++i) ok &= okarr[i];
        sinfo[0] = ok;
    }
}

// ---------- fallback: full histogram (early-exit when speculation ok) ----------
__global__ __launch_bounds__(TPB, 2) void k_hist_fb(const float* __restrict__ pred,
                                                    const float* __restrict__ targ,
                                                    int nvec,
                                                    const unsigned* __restrict__ sinfo,
                                                    unsigned short* __restrict__ hist16)
{
    if (sinfo[0]) return;
    __shared__ unsigned h[2 * NBINS];
    for (int k = threadIdx.x; k < 2 * NBINS; k += TPB) h[k] = 0u;
    __syncthreads();

    const int b = blockIdx.y;
    const float4* __restrict__ p4 = (const float4*)pred + (size_t)b * nvec;
    const float4* __restrict__ t4 = (const float4*)targ + (size_t)b * nvec;
    const int S  = BPB * TPB;
    const int i0 = blockIdx.x * TPB + threadIdx.x;

#define PELH(tq, pq)                                             \
    {                                                            \
        float tv[4] = {tq.x, tq.y, tq.z, tq.w};                  \
        float pv[4] = {pq.x, pq.y, pq.z, pq.w};                  \
        _Pragma("unroll")                                        \
        for (int j = 0; j < 4; ++j) {                            \
            float tt = tv[j], pp = pv[j];                        \
            if (tt > 0.01f) {                                    \
                atomicAdd(&h[bucketOf(tt)], 1u);                 \
                if (pp > 0.f)                                    \
                    atomicAdd(&h[NBINS + bucketOf(pp)], 1u);     \
            }                                                    \
        }                                                        \
    }
#define PROCH(SET)                                               \
    {                                                            \
        PELH(t##SET##0, p##SET##0); PELH(t##SET##1, p##SET##1);  \
        PELH(t##SET##2, p##SET##2); PELH(t##SET##3, p##SET##3);  \
    }
    float4 tA0, tA1, tA2, tA3, pA0, pA1, pA2, pA3;
    float4 tB0, tB1, tB2, tB3, pB0, pB1, pB2, pB3;
    PIPELINE8(PROCH)
#undef PROCH
#undef PELH
    __syncthreads();

    unsigned short* gh = hist16 + ((size_t)b * BPB + blockIdx.x) * (2 * NBINS);
    ushort4* gh4 = (ushort4*)gh;
    for (int k = threadIdx.x; k < (2 * NBINS) / 4; k += TPB) {
        ushort4 v;
        v.x = (unsigned short)h[4 * k + 0];
        v.y = (unsigned short)h[4 * k + 1];
        v.z = (unsigned short)h[4 * k + 2];
        v.w = (unsigned short)h[4 * k + 3];
        gh4[k] = v;
    }
}

// ---------- fallback: scan histogram -> binfo ----------
// binfo per bt (8 u32): 0 lo, 1 hi, 2 cum_below, 3 k, 4 frac, 5 nv
__global__ __launch_bounds__(256) void k_scan_fb(const unsigned short* __restrict__ hist16,
                                                 const unsigned* __restrict__ cnt,
                                                 const unsigned* __restrict__ sinfo,
                                                 unsigned* __restrict__ binfo)
{
    if (sinfo[0]) return;
    const int bt = blockIdx.x;
    const int b = bt >> 1, t = bt & 1;
    const unsigned nv = cnt[b * 8 + t];
    unsigned* bi = binfo + bt * 8;

    __shared__ unsigned partial[256];
    __shared__ unsigned sk, sr2;

    if (threadIdx.x == 0) {
        bi[5] = nv;
        if (nv == 0) {
            bi[0] = 0xFFFFFFFFu; bi[1] = 0xFFFFFFFFu;
            bi[2] = 0; bi[3] = 0; bi[4] = __float_as_uint(0.0f);
        } else {
            double pos  = 0.9 * (double)(nv - 1);
            unsigned k  = (unsigned)pos;
            bi[3] = k;
            bi[4] = __float_as_uint((float)(pos - (double)k));
            sk = k;
            sr2 = (k + 2 <= nv) ? (k + 2) : (k + 1);
        }
    }
    __syncthreads();
    if (nv == 0) return;

    const unsigned r1 = sk + 1, r2 = sr2;
    const int lo = threadIdx.x * (NBINS / 256);
    unsigned local[NBINS / 256];
#pragma unroll
    for (int j = 0; j < NBINS / 256; ++j) local[j] = 0;
    for (int rep = 0; rep < BPB; ++rep) {
        const ushort4* h4 = (const ushort4*)(hist16 +
            ((size_t)b * BPB + rep) * (2 * NBINS) + (size_t)t * NBINS + lo);
        ushort4 a = h4[0], c = h4[1];
        local[0] += a.x; local[1] += a.y; local[2] += a.z; local[3] += a.w;
        local[4] += c.x; local[5] += c.y; local[6] += c.z; local[7] += c.w;
    }
    unsigned ls = 0;
#pragma unroll
    for (int j = 0; j < NBINS / 256; ++j) ls += local[j];
    partial[threadIdx.x] = ls;
    __syncthreads();
    for (int off = 1; off < 256; off <<= 1) {
        unsigned v = (threadIdx.x >= (unsigned)off) ? partial[threadIdx.x - off] : 0u;
        __syncthreads();
        partial[threadIdx.x] += v;
        __syncthreads();
    }
    unsigned run = partial[threadIdx.x] - ls;
#pragma unroll
    for (int j = 0; j < NBINS / 256; ++j) {
        unsigned c = local[j];
        if (c) {
            if (run < r1 && run + c >= r1) { bi[0] = lo + j; bi[2] = run; }
            if (run < r2 && run + c >= r2) { bi[1] = lo + j; }
        }
        run += c;
    }
}

// ---------- fallback: compact by bucket range ----------
__global__ __launch_bounds__(TPB, 2) void k_compact_fb(const float* __restrict__ pred,
                                                       const float* __restrict__ targ,
                                                       int nvec,
                                                       const unsigned* __restrict__ sinfo,
                                                       const unsigned* __restrict__ binfo,
                                                       unsigned* __restrict__ fb_npairs,
                                                       unsigned* __restrict__ fb_naa,
                                                       float2* __restrict__ fb_pairs)
{
    if (sinfo[0]) return;
    __shared__ float2   sbuf[FB_LCAP];
    __shared__ unsigned scnt, sbase;
    if (threadIdx.x == 0) scnt = 0;
    __syncthreads();

    const int b = blockIdx.y;
    const unsigned lo_t = binfo[(2 * b + 0) * 8 + 0], hi_t = binfo[(2 * b + 0) * 8 + 1];
    const unsigned lo_p = binfo[(2 * b + 1) * 8 + 0], hi_p = binfo[(2 * b + 1) * 8 + 1];

    const float4* __restrict__ p4 = (const float4*)pred + (size_t)b * nvec;
    const float4* __restrict__ t4 = (const float4*)targ + (size_t)b * nvec;
    unsigned laa = 0;
    const int S  = BPB * TPB;
    const int i0 = blockIdx.x * TPB + threadIdx.x;

#define PELC(tq, pq)                                                      \
    {                                                                     \
        float tv[4] = {tq.x, tq.y, tq.z, tq.w};                           \
        float pv[4] = {pq.x, pq.y, pq.z, pq.w};                           \
        _Pragma("unroll")                                                 \
        for (int j = 0; j < 4; ++j) {                                     \
            float tt = tv[j], pp = pv[j];                                 \
            if (tt > 0.01f) {                                             \
                unsigned at = bucketOf(tt);                               \
                bool t_in = (at >= lo_t) && (at <= hi_t);                 \
                bool t_ab = (at > hi_t);                                  \
                bool ppos = (pp > 0.f);                                   \
                unsigned ap = bucketOf(pp);                               \
                bool p_in = ppos && (ap >= lo_p) && (ap <= hi_p);         \
                bool p_ab = ppos && (ap > hi_p);                          \
                if (t_ab && p_ab) laa++;                                  \
                if (t_in || p_in) {                                       \
                    unsigned idx = atomicAdd(&scnt, 1u);                  \
                    if (idx < FB_LCAP) sbuf[idx] = make_float2(tt, pp);   \
                }                                                         \
            }                                                             \
        }                                                                 \
    }
#define PROCC(SET)                                               \
    {                                                            \
        PELC(t##SET##0, p##SET##0); PELC(t##SET##1, p##SET##1);  \
        PELC(t##SET##2, p##SET##2); PELC(t##SET##3, p##SET##3);  \
    }
    float4 tA0, tA1, tA2, tA3, pA0, pA1, pA2, pA3;
    float4 tB0, tB1, tB2, tB3, pB0, pB1, pB2, pB3;
    PIPELINE8(PROCC)
#undef PROCC
#undef PELC
    __syncthreads();
    if (threadIdx.x == 0) {
        unsigned n = scnt < FB_LCAP ? scnt : FB_LCAP;
        sbase = atomicAdd(&fb_npairs[b], n);
        scnt = n;
    }
    __syncthreads();
    for (unsigned k = threadIdx.x; k < scnt; k += TPB) {
        unsigned idx = sbase + k;
        if (idx < FB_PCAP) fb_pairs[(size_t)b * FB_PCAP + idx] = sbuf[k];
    }
    for (int off = 32; off; off >>= 1) laa += __shfl_down(laa, off);
    if ((threadIdx.x & 63) == 0 && laa) atomicAdd(&fb_naa[b], laa);
}

// ---------- k_select: refine-histogram -> exact order stats -> threshold + hot ----------
__global__ __launch_bounds__(1024) void k_select(const unsigned* __restrict__ sinfo,
                                                 const unsigned* __restrict__ cnt,
                                                 const float2* __restrict__ pairs,
                                                 const unsigned* __restrict__ binfo,
                                                 const unsigned* __restrict__ fb_npairs,
                                                 const float2* __restrict__ fb_pairs,
                                                 float* __restrict__ thr,
                                                 unsigned* __restrict__ hotc)
{
    __shared__ unsigned hc[2048];     // hist, then inclusive cum in-place
    __shared__ unsigned partial[1024];
    __shared__ float    sv[CCAP];
    __shared__ unsigned sb_lo, sb_hi, scc, scle;
    __shared__ float    sth;

    const int bt = blockIdx.x;
    const int b = bt >> 1, t = bt & 1;
    const unsigned ok = sinfo[0];

    unsigned k, below, nv;
    float frac, rlo, rhi;
    unsigned blo_bk = 0, bhi_bk = 0;
    const float2* src;
    unsigned np;

    if (ok) {
        const unsigned* si = sinfo + 8 + bt * 8;
        k = si[0]; frac = __uint_as_float(si[1]); below = si[2]; nv = si[3];
        rlo = WLO; rhi = WHI;
        src = pairs + (size_t)b * PCAP;
        np = cnt[b * 8 + 7]; if (np > PCAP) np = PCAP;
    } else {
        const unsigned* bi = binfo + bt * 8;
        nv = bi[5];
        if (nv == 0) {
            if (threadIdx.x == 0) { thr[bt] = 0.01f; hotc[bt] = 0; }
            return;
        }
        blo_bk = bi[0]; bhi_bk = bi[1]; below = bi[2]; k = bi[3];
        frac = __uint_as_float(bi[4]);
        rlo = (float)blo_bk * (1.0f / NBINS);
        rhi = (float)(bhi_bk + 1) * (1.0f / NBINS);
        src = fb_pairs + (size_t)b * FB_PCAP;
        np = fb_npairs[b]; if (np > FB_PCAP) np = FB_PCAP;
    }
    const float scale = 2048.0f / (rhi - rlo);

#define MEMB(v) (ok ? ((v) >= WLO && (v) < WHI)                                   \
                    : ((v) > 0.f && bucketOf(v) >= blo_bk && bucketOf(v) <= bhi_bk))

    for (int i = threadIdx.x; i < 2048; i += 1024) hc[i] = 0u;
    if (threadIdx.x == 0) { sb_lo = 0xFFFFFFFFu; sb_hi = 0xFFFFFFFFu; scc = 0; scle = 0; }
    __syncthreads();

    // phase A: refine histogram
    for (unsigned i = threadIdx.x; i < np; i += 1024) {
        float2 pr = src[i];
        float v = t ? pr.y : pr.x;
        if (MEMB(v)) {
            int bin = (int)((v - rlo) * scale);
            bin = bin < 0 ? 0 : (bin > 2047 ? 2047 : bin);
            atomicAdd(&hc[bin], 1u);
        }
    }
    __syncthreads();

    // inclusive prefix over 2048 bins (2 per thread)
    unsigned h0 = hc[2 * threadIdx.x], h1 = hc[2 * threadIdx.x + 1];
    unsigned ssum = h0 + h1;
    partial[threadIdx.x] = ssum;
    __syncthreads();
    for (int off = 1; off < 1024; off <<= 1) {
        unsigned v = (threadIdx.x >= (unsigned)off) ? partial[threadIdx.x - off] : 0u;
        __syncthreads();
        partial[threadIdx.x] += v;
        __syncthreads();
    }
    unsigned excl = partial[threadIdx.x] - ssum;
    hc[2 * threadIdx.x]     = excl + h0;
    hc[2 * threadIdx.x + 1] = excl + ssum;
    __syncthreads();

    // locate bins containing local ranks r+1, r+2
    const unsigned r  = k - below;
    const unsigned r1 = r + 1, r2 = r + 2;
    for (int j = 2 * threadIdx.x; j <= 2 * threadIdx.x + 1; ++j) {
        unsigned c = hc[j];
        unsigned prev = (j == 0) ? 0u : hc[j - 1];
        if (c >= r1 && prev < r1) atomicMin(&sb_lo, (unsigned)j);
        if (c >= r2 && prev < r2) atomicMin(&sb_hi, (unsigned)j);
    }
    __syncthreads();
    unsigned b_lo = sb_lo, b_hi = sb_hi;
    if (b_hi == 0xFFFFFFFFu) b_hi = 2047;
    if (b_lo == 0xFFFFFFFFu) b_lo = 2047;
    unsigned cumlo = (b_lo > 0) ? hc[b_lo - 1] : 0u;

    // phase B: compact values in [b_lo, b_hi]
    for (unsigned i = threadIdx.x; i < np; i += 1024) {
        float2 pr = src[i];
        float v = t ? pr.y : pr.x;
        if (MEMB(v)) {
            int bin = (int)((v - rlo) * scale);
            bin = bin < 0 ? 0 : (bin > 2047 ? 2047 : bin);
            if ((unsigned)bin >= b_lo && (unsigned)bin <= b_hi) {
                unsigned idx = atomicAdd(&scc, 1u);
                if (idx < CCAP) sv[idx] = v;
            }
        }
    }
    __syncthreads();
    unsigned n_cmp = scc < CCAP ? scc : CCAP;

    // odd-even transposition sort (n_cmp small, typically ~25)
    for (unsigned ph = 0; ph < n_cmp; ++ph) {
        unsigned idx = 2 * threadIdx.x + (ph & 1);
        if (idx + 1 < n_cmp) {
            float a = sv[idx], c = sv[idx + 1];
            if (a > c) { sv[idx] = c; sv[idx + 1] = a; }
        }
        __syncthreads();
    }

    if (threadIdx.x == 0) {
        long rl = (long)r - (long)cumlo;
        if (rl < 0) rl = 0;
        if (rl >= (long)n_cmp) rl = (long)n_cmp - 1;
        float v0 = sv[rl];
        float v1 = (rl + 1 < (long)n_cmp) ? sv[rl + 1] : v0;
        sth = v0 + frac * (v1 - v0);
        thr[bt] = sth;
    }
    __syncthreads();
    float th = sth;

    // phase C: tie-safe count of member values <= th
    unsigned cle = 0;
    for (unsigned i = threadIdx.x; i < np; i += 1024) {
        float2 pr = src[i];
        float v = t ? pr.y : pr.x;
        if (MEMB(v) && v <= th) cle++;
    }
    for (int off = 32; off; off >>= 1) cle += __shfl_down(cle, off);
    if ((threadIdx.x & 63) == 0 && cle) atomicAdd(&scle, cle);
    __syncthreads();
    if (threadIdx.x == 0) hotc[bt] = nv - below - scle;
#undef MEMB
}

// ---------- k_resolve: per-batch intersection + loss ----------
__global__ __launch_bounds__(256) void k_resolve(const unsigned* __restrict__ sinfo,
                                                 const double* __restrict__ sse,
                                                 const unsigned* __restrict__ cnt,
                                                 const float2* __restrict__ pairs,
                                                 const unsigned* __restrict__ fb_npairs,
                                                 const unsigned* __restrict__ fb_naa,
                                                 const float2* __restrict__ fb_pairs,
                                                 const float* __restrict__ thr,
                                                 const unsigned* __restrict__ hotc,
                                                 double* __restrict__ loss_part)
{
    __shared__ unsigned sI;
    if (threadIdx.x == 0) sI = 0;
    __syncthreads();
    const int b = blockIdx.x;
    const unsigned ok = sinfo[0];
    const float2* src = ok ? (pairs + (size_t)b * PCAP) : (fb_pairs + (size_t)b * FB_PCAP);
    unsigned np  = ok ? cnt[b * 8 + 7] : fb_npairs[b];
    unsigned cap = ok ? PCAP : FB_PCAP;
    if (np > cap) np = cap;
    unsigned naa = ok ? cnt[b * 8 + 6] : fb_naa[b];

    float th_t = thr[2 * b + 0], th_p = thr[2 * b + 1];
    unsigned c = 0;
    for (unsigned i = threadIdx.x; i < np; i += 256) {
        float2 pr = src[i];
        if (pr.x > th_t && pr.y > th_p) c++;
    }
    for (int off = 32; off; off >>= 1) c += __shfl_down(c, off);
    if ((threadIdx.x & 63) == 0 && c) atomicAdd(&sI, c);
    __syncthreads();
    if (threadIdx.x == 0) {
        double nv  = (double)cnt[b * 8 + 0];
        double mse = sse[b] / (nv + 1e-8);
        double T = (double)hotc[2 * b + 0];
        double P = (double)hotc[2 * b + 1];
        double I = (double)(naa + sI);
        double dice = 1.0 - 2.0 * I / (P + T + 1e-8);
        loss_part[b] = 0.5 * mse + 0.5 * dice;
    }
}

__global__ void k_final(const double* __restrict__ loss_part, float* __restrict__ out)
{
    if (threadIdx.x == 0 && blockIdx.x == 0) {
        double acc = 0.0;
        for (int b = 0; b < NB; ++b) acc += loss_part[b];
        out[0] = (float)(acc / (double)NB);
    }
}

// ---------- launcher ----------
extern "C" void kernel_launch(void* const* d_in, const int* in_sizes, int n_in,
                              void* d_out, int out_size, void* d_ws, size_t ws_size,
                              hipStream_t stream) {
    const float* pred = (const float*)d_in[0];
    const float* targ = (const float*)d_in[1];
    float* out = (float*)d_out;

    const int total = in_sizes[0];
    const int N     = total / NB;   // 2,097,152
    const int nvec  = N / 4;        // 524,288 == BPB*TPB*4*8 exactly

    // ws layout:
    // [0, 4194304): pairs_spec (8*57344*8 = 3,670,016) overlapped with fb hist16 (8*64*2*2048*2 = 4,194,304)
    char* ws = (char*)d_ws;
    float2*         pairs  = (float2*)(ws + 0);
    unsigned short* hist16 = (unsigned short*)(ws + 0);
    double*   sse       = (double*)  (ws + 4194304);
    unsigned* cnt       = (unsigned*)(ws + 4194368);
    unsigned* oflow     = (unsigned*)(ws + 4194624);
    unsigned* fb_naa    = (unsigned*)(ws + 4194688);
    unsigned* fb_npairs = (unsigned*)(ws + 4194752);
    double*   loss_part = (double*)  (ws + 4194816);
    unsigned* sinfo     = (unsigned*)(ws + 4194880);
    unsigned* binfo     = (unsigned*)(ws + 4195904);
    float*    thr       = (float*)   (ws + 4196416);
    unsigned* hotc      = (unsigned*)(ws + 4196480);
    float2*   fb_pairs  = (float2*)  (ws + 4196544);   // 8*8192*8 = 524,288 -> ends 4,720,832
    (void)ws_size; (void)n_in; (void)out_size;

    hipMemsetAsync(ws + 4194304, 0, 512, stream);  // sse, cnt, oflow, fb_naa, fb_npairs

    dim3 gs(BPB, NB);
    k_main      <<<gs, TPB, 0, stream>>>(pred, targ, nvec, sse, cnt, oflow, pairs);
    k_check     <<<1, 64, 0, stream>>>(cnt, oflow, sinfo);
    k_hist_fb   <<<gs, TPB, 0, stream>>>(pred, targ, nvec, sinfo, hist16);
    k_scan_fb   <<<2 * NB, 256, 0, stream>>>(hist16, cnt, sinfo, binfo);
    k_compact_fb<<<gs, TPB, 0, stream>>>(pred, targ, nvec, sinfo, binfo, fb_npairs, fb_naa, fb_pairs);
    k_select    <<<2 * NB, 1024, 0, stream>>>(sinfo, cnt, pairs, binfo, fb_npairs, fb_pairs, thr, hotc);
    k_resolve   <<<NB, 256, 0, stream>>>(sinfo, sse, cnt, pairs, fb_npairs, fb_naa, fb_pairs, thr, hotc, loss_part);
    k_final     <<<1, 64, 0, stream>>>(loss_part, out);
}